// Round 2
// baseline (24318.253 us; speedup 1.0000x reference)
//
#include <hip/hip_runtime.h>
#include <stdint.h>
#include <stddef.h>

// Problem dims
#define T_LEN 2048
#define BATCH 64
#define DDIM  512
#define HDIM  512
#define G4    2048   // 4*H

typedef short  short8  __attribute__((ext_vector_type(8)));
typedef float  f32x4   __attribute__((ext_vector_type(4)));

static __device__ __forceinline__ unsigned short f2bf(float f) {
  unsigned int u = __builtin_bit_cast(unsigned int, f);
  u += 0x7FFFu + ((u >> 16) & 1u);          // round-to-nearest-even
  return (unsigned short)(u >> 16);
}
static __device__ __forceinline__ float bf2f(unsigned short s) {
  unsigned int u = ((unsigned int)s) << 16;
  return __builtin_bit_cast(float, u);
}
static __device__ __forceinline__ float sigm(float x) {
  return 1.f / (1.f + __expf(-x));
}
static __device__ __forceinline__ float tanh_f(float x) {
  float a = fabsf(x);
  float e = __expf(2.f * a);                 // overflow-safe: e=inf -> r=1
  float r = 1.f - 2.f / (e + 1.f);
  return x < 0.f ? -r : r;
}

// ---------------------------------------------------------------------------
// Kernel 1: x (fp32) -> xb (bf16), flat [B*T][D]
// ---------------------------------------------------------------------------
__global__ __launch_bounds__(256) void k_xconv(const float* __restrict__ x,
                                               unsigned short* __restrict__ xb,
                                               long n4) {
  long i = (long)blockIdx.x * 256 + threadIdx.x;
  long stride = (long)gridDim.x * 256;
  for (; i < n4; i += stride) {
    f32x4 v = *(((const f32x4*)x) + i);
    unsigned long long pk = (unsigned long long)f2bf(v[0])
                          | ((unsigned long long)f2bf(v[1]) << 16)
                          | ((unsigned long long)f2bf(v[2]) << 32)
                          | ((unsigned long long)f2bf(v[3]) << 48);
    *(((unsigned long long*)xb) + i) = pk;
  }
}

// ---------------------------------------------------------------------------
// Kernel 2: build WiT[g][k] = Wi[k][hc(g)] (bf16), WhT[g][k] = Wh[k][hc(g)],
//           bsum[g] = b_i[gate][hc] + b_h[gate][hc]   (g = gate*512 + hc)
// ---------------------------------------------------------------------------
__global__ __launch_bounds__(256) void k_prep(
    const float* wi0, const float* wi1, const float* wi2, const float* wi3,
    const float* wh0, const float* wh1, const float* wh2, const float* wh3,
    const float* bi0, const float* bi1, const float* bi2, const float* bi3,
    const float* bh0, const float* bh1, const float* bh2, const float* bh3,
    unsigned short* __restrict__ WiT, unsigned short* __restrict__ WhT,
    float* __restrict__ bsum) {
  const float* wis[4] = {wi0, wi1, wi2, wi3};
  const float* whs[4] = {wh0, wh1, wh2, wh3};
  const float* bis[4] = {bi0, bi1, bi2, bi3};
  const float* bhs[4] = {bh0, bh1, bh2, bh3};
  int stride = gridDim.x * 256;
  for (int idx = blockIdx.x * 256 + threadIdx.x; idx < 2 * 1048576 + 2048; idx += stride) {
    if (idx < 1048576) {
      int g = idx >> 9, k = idx & 511;
      int gate = g >> 9, hc = g & 511;
      WiT[idx] = f2bf(wis[gate][k * 512 + hc]);
    } else if (idx < 2097152) {
      int j = idx - 1048576;
      int g = j >> 9, k = j & 511;
      int gate = g >> 9, hc = g & 511;
      WhT[j] = f2bf(whs[gate][k * 512 + hc]);
    } else {
      int g = idx - 2097152;
      int gate = g >> 9, hc = g & 511;
      bsum[g] = bis[gate][hc] + bhs[gate][hc];
    }
  }
}

// ---------------------------------------------------------------------------
// Kernel 3: input GEMM  G[t][b][g] = sum_k xb[b*T+t][k] * WiT[g][k]   (bf16 out)
// 128x128 tile, BK=64, 256 thr (4 waves 2x2), 16x16x32 bf16 MFMA,
// XOR-swizzled LDS (row pitch 128B, key (row&7)<<4).
// ---------------------------------------------------------------------------
__global__ __launch_bounds__(256) void k_igemm(const unsigned short* __restrict__ xb,
                                               const unsigned short* __restrict__ WiT,
                                               unsigned short* __restrict__ G) {
  __shared__ char As[16384];
  __shared__ char Bs[16384];
  const int tid  = threadIdx.x;
  const int lane = tid & 63;
  const int wave = tid >> 6;
  const int wm = wave >> 1, wn = wave & 1;
  const int r0 = blockIdx.x * 128;          // rows in [B*T] space (one b per tile)
  const int g0 = blockIdx.y * 128;
  const int bidx = r0 >> 11;
  const int t0   = r0 & 2047;

  f32x4 acc[4][4];
  f32x4 zero = {0.f, 0.f, 0.f, 0.f};
#pragma unroll
  for (int mi = 0; mi < 4; ++mi)
#pragma unroll
    for (int ni = 0; ni < 4; ++ni) acc[mi][ni] = zero;

  for (int kb = 0; kb < 8; ++kb) {
#pragma unroll
    for (int q = 0; q < 4; ++q) {
      int u = tid + q * 256;                // < 1024
      int row = u >> 3, seg = u & 7;        // 8 x 16B per 128B row
      short8 va = *(const short8*)(xb + (size_t)(r0 + row) * 512 + kb * 64 + seg * 8);
      *(short8*)(As + row * 128 + ((seg * 16) ^ ((row & 7) << 4))) = va;
      short8 vb = *(const short8*)(WiT + (size_t)(g0 + row) * 512 + kb * 64 + seg * 8);
      *(short8*)(Bs + row * 128 + ((seg * 16) ^ ((row & 7) << 4))) = vb;
    }
    __syncthreads();
#pragma unroll
    for (int kt = 0; kt < 2; ++kt) {
      int kby = kt * 64 + ((lane >> 4) << 4);
      short8 af[4], bfr[4];
#pragma unroll
      for (int mi = 0; mi < 4; ++mi) {
        int row = wm * 64 + mi * 16 + (lane & 15);
        af[mi] = *(const short8*)(As + row * 128 + (kby ^ ((row & 7) << 4)));
      }
#pragma unroll
      for (int ni = 0; ni < 4; ++ni) {
        int row = wn * 64 + ni * 16 + (lane & 15);
        bfr[ni] = *(const short8*)(Bs + row * 128 + (kby ^ ((row & 7) << 4)));
      }
#pragma unroll
      for (int mi = 0; mi < 4; ++mi)
#pragma unroll
        for (int ni = 0; ni < 4; ++ni)
          acc[mi][ni] = __builtin_amdgcn_mfma_f32_16x16x32_bf16(af[mi], bfr[ni], acc[mi][ni], 0, 0, 0);
    }
    __syncthreads();
  }
  // epilogue: D row = (lane>>4)*4+reg (M), col = lane&15 (N); out layout [t][b][g]
#pragma unroll
  for (int mi = 0; mi < 4; ++mi) {
#pragma unroll
    for (int r = 0; r < 4; ++r) {
      int m = wm * 64 + mi * 16 + ((lane >> 4) << 2) + r;
      size_t orow = ((size_t)(t0 + m) * 64 + bidx) * 2048;
#pragma unroll
      for (int ni = 0; ni < 4; ++ni) {
        int n = wn * 64 + ni * 16 + (lane & 15);
        __builtin_nontemporal_store(f2bf(acc[mi][ni][r]), G + orow + g0 + n);
      }
    }
  }
}

// ---------------------------------------------------------------------------
// Kernel 4: persistent LSTM recurrence.
// 64 WGs x 512 thr. WG w owns h-cols [w*8, w*8+8) => 32 gate cols (packed
// [i8|f8|g8|o8]). Wh slice LDS-resident (32KB). Per step: flag-poll barrier,
// stage full h_t (64KB bf16) via agent loads, 8 waves x 16 MFMA, gates, c in
// regs, publish h slice + flag. Double-buffered h, per-step monotone flags.
// ---------------------------------------------------------------------------
__global__ __launch_bounds__(512) void k_rec(const unsigned short* __restrict__ G,
                                             const unsigned short* __restrict__ WhT,
                                             const float* __restrict__ bsum,
                                             unsigned short* hb0, unsigned short* hb1,
                                             int* flags, float* __restrict__ out) {
  extern __shared__ char smem[];
  char*  Hs   = smem;                        // [64][1024B] swizzled, 64KB
  char*  Bsl  = smem + 65536;                // [32][1024B] swizzled, 32KB
  float* gbuf = (float*)(smem + 98304);      // [64][32] f32, 8KB

  const int tid  = threadIdx.x;
  const int lane = tid & 63;
  const int wave = tid >> 6;
  const int w    = blockIdx.x;               // 0..63
  const int mt   = wave & 3, nt = wave >> 2;
  const int bb   = tid >> 3;                 // batch row (elementwise phase)
  const int jj   = tid & 7;
  const int hc   = w * 8 + jj;

  // Wh slice -> LDS (swizzled), stays resident
#pragma unroll
  for (int q = 0; q < 4; ++q) {
    int u = tid + q * 512;                   // < 2048 (32 rows x 64 segs of 16B)
    int p = u >> 6, seg = u & 63;
    int grow = (p >> 3) * 512 + w * 8 + (p & 7);
    short8 v = *(const short8*)(WhT + (size_t)grow * 512 + seg * 8);
    *(short8*)(Bsl + p * 1024 + ((seg * 16) ^ ((p & 7) << 4))) = v;
  }
  // zero h_0 slice (agent-visible)
  if ((jj & 1) == 0)
    __hip_atomic_store((unsigned int*)hb0 + ((bb * 512 + hc) >> 1), 0u,
                       __ATOMIC_RELAXED, __HIP_MEMORY_SCOPE_AGENT);
  float c = 0.f;
  float bias0 = bsum[hc], bias1 = bsum[512 + hc], bias2 = bsum[1024 + hc], bias3 = bsum[1536 + hc];

  asm volatile("s_waitcnt vmcnt(0)" ::: "memory");
  __syncthreads();
  if (tid == 0) {
    __threadfence();
    __hip_atomic_store(flags + w, 1, __ATOMIC_RELEASE, __HIP_MEMORY_SCOPE_AGENT);
  }

  for (int t = 0; t < T_LEN; ++t) {
    // ---- prefetch this step's input-projection gates (h-independent):
    // issue the 4 HBM loads BEFORE the poll so their latency hides under it.
    size_t gbase = ((size_t)t * 64 + bb) * 2048;
    float xi = bf2f(G[gbase + hc]);
    float xf = bf2f(G[gbase + 512 + hc]);
    float xg = bf2f(G[gbase + 1024 + hc]);
    float xo = bf2f(G[gbase + 1536 + hc]);

    // ---- barrier: wait for all WGs to have published h_t ----
    if (wave == 0) {
      int target = t + 1;
      while (1) {
        int f = __hip_atomic_load(flags + lane, __ATOMIC_ACQUIRE, __HIP_MEMORY_SCOPE_AGENT);
        if (__all(f >= target)) break;
        __builtin_amdgcn_s_sleep(1);
      }
    }
    __syncthreads();

    const unsigned long long* hin = (const unsigned long long*)((t & 1) ? hb1 : hb0);
    unsigned short* hout = (t & 1) ? hb0 : hb1;

    // ---- stage h_t [64][512] bf16 -> LDS (swizzled) ----
#pragma unroll
    for (int q = 0; q < 16; ++q) {
      int u = tid + q * 512;                 // < 8192 (8B granules)
      int row = u >> 7, gr = u & 127;
      unsigned long long v = __hip_atomic_load(hin + u, __ATOMIC_RELAXED, __HIP_MEMORY_SCOPE_AGENT);
      *(unsigned long long*)(Hs + row * 1024 + ((gr * 8) ^ ((row & 7) << 4))) = v;
    }
    __syncthreads();

    // ---- h_t @ Wh_slice : [64x512]x[512x32] ----
    f32x4 acc = {0.f, 0.f, 0.f, 0.f};
#pragma unroll
    for (int kt = 0; kt < 16; ++kt) {
      int kby = kt * 64 + ((lane >> 4) << 4);
      int arow = mt * 16 + (lane & 15);
      short8 a  = *(const short8*)(Hs  + arow * 1024 + (kby ^ ((arow & 7) << 4)));
      int brow = nt * 16 + (lane & 15);
      short8 bv = *(const short8*)(Bsl + brow * 1024 + (kby ^ ((brow & 7) << 4)));
      acc = __builtin_amdgcn_mfma_f32_16x16x32_bf16(a, bv, acc, 0, 0, 0);
    }
    {
      int m  = mt * 16 + ((lane >> 4) << 2);
      int pc = nt * 16 + (lane & 15);
      gbuf[(m + 0) * 32 + pc] = acc[0];
      gbuf[(m + 1) * 32 + pc] = acc[1];
      gbuf[(m + 2) * 32 + pc] = acc[2];
      gbuf[(m + 3) * 32 + pc] = acc[3];
    }
    __syncthreads();

    // ---- gates + state update (thread = (batch bb, h-col jj)) ----
    xi += gbuf[bb * 32 + jj]      + bias0;
    xf += gbuf[bb * 32 + 8 + jj]  + bias1;
    xg += gbuf[bb * 32 + 16 + jj] + bias2;
    xo += gbuf[bb * 32 + 24 + jj] + bias3;
    float iv = sigm(xi), fv = sigm(xf), gv = tanh_f(xg), ov = sigm(xo);
    c = fv * c + iv * gv;
    float h = ov * tanh_f(c);

    // publish h slice (pack bf16 pairs -> u32 agent stores)
    unsigned short hu = f2bf(h);
    unsigned int other = __shfl_xor((unsigned int)hu, 1);
    if ((jj & 1) == 0) {
      unsigned int val = (unsigned int)hu | (other << 16);
      __hip_atomic_store((unsigned int*)hout + ((bb * 512 + hc) >> 1), val,
                         __ATOMIC_RELAXED, __HIP_MEMORY_SCOPE_AGENT);
    }
    asm volatile("s_waitcnt vmcnt(0)" ::: "memory");
    __syncthreads();
    if (tid == 0) {
      __threadfence();
      __hip_atomic_store(flags + w, t + 2, __ATOMIC_RELEASE, __HIP_MEMORY_SCOPE_AGENT);
    }
    if (t == T_LEN - 1) {
      out[bb * 512 + hc] = h;                // h_T
      out[32768 + bb * 512 + hc] = c;        // c_T
    }
  }
}

// ---------------------------------------------------------------------------
extern "C" void kernel_launch(void* const* d_in, const int* in_sizes, int n_in,
                              void* d_out, int out_size, void* d_ws, size_t ws_size,
                              hipStream_t stream) {
  const float* x   = (const float*)d_in[0];
  const float* wi0 = (const float*)d_in[1];
  const float* wi1 = (const float*)d_in[2];
  const float* wi2 = (const float*)d_in[3];
  const float* wi3 = (const float*)d_in[4];
  const float* wh0 = (const float*)d_in[5];
  const float* wh1 = (const float*)d_in[6];
  const float* wh2 = (const float*)d_in[7];
  const float* wh3 = (const float*)d_in[8];
  const float* bi0 = (const float*)d_in[9];
  const float* bi1 = (const float*)d_in[10];
  const float* bi2 = (const float*)d_in[11];
  const float* bi3 = (const float*)d_in[12];
  const float* bh0 = (const float*)d_in[13];
  const float* bh1 = (const float*)d_in[14];
  const float* bh2 = (const float*)d_in[15];
  const float* bh3 = (const float*)d_in[16];

  char* ws = (char*)d_ws;
  unsigned short* xb   = (unsigned short*)(ws);                               // 134217728 B
  unsigned short* G    = (unsigned short*)(ws + 134217728);                   // 536870912 B
  unsigned short* WiT  = (unsigned short*)(ws + 671088640);                   // 2097152 B
  unsigned short* WhT  = (unsigned short*)(ws + 673185792);                   // 2097152 B
  float*          bsum = (float*)         (ws + 675282944);                   // 8192 B
  unsigned short* hb0  = (unsigned short*)(ws + 675291136);                   // 65536 B
  unsigned short* hb1  = (unsigned short*)(ws + 675356672);                   // 65536 B
  int*            flags= (int*)           (ws + 675422208);                   // 256 B
  float* out = (float*)d_out;

  (void)hipFuncSetAttribute(reinterpret_cast<const void*>(k_rec),
                            hipFuncAttributeMaxDynamicSharedMemorySize, 106496);

  k_xconv<<<8192, 256, 0, stream>>>(x, xb, 16777216L);
  k_prep<<<2048, 256, 0, stream>>>(wi0, wi1, wi2, wi3, wh0, wh1, wh2, wh3,
                                   bi0, bi1, bi2, bi3, bh0, bh1, bh2, bh3,
                                   WiT, WhT, bsum);
  k_igemm<<<dim3(1024, 16), 256, 0, stream>>>(xb, WiT, G);
  k_rec<<<64, 512, 106496, stream>>>(G, WhT, bsum, hb0, hb1, flags, out);
}

// Round 5
// 14782.137 us; speedup vs baseline: 1.6451x; 1.6451x over previous
//
#include <hip/hip_runtime.h>
#include <stdint.h>
#include <stddef.h>

// Problem dims
#define T_LEN 2048
#define BATCH 64
#define DDIM  512
#define HDIM  512
#define G4    2048   // 4*H

typedef short  short8  __attribute__((ext_vector_type(8)));
typedef float  f32x4   __attribute__((ext_vector_type(4)));

static __device__ __forceinline__ unsigned short f2bf(float f) {
  unsigned int u = __builtin_bit_cast(unsigned int, f);
  u += 0x7FFFu + ((u >> 16) & 1u);          // round-to-nearest-even
  return (unsigned short)(u >> 16);
}
static __device__ __forceinline__ float bf2f(unsigned short s) {
  unsigned int u = ((unsigned int)s) << 16;
  return __builtin_bit_cast(float, u);
}
static __device__ __forceinline__ float sigm(float x) {
  return 1.f / (1.f + __expf(-x));
}
static __device__ __forceinline__ float tanh_f(float x) {
  float a = fabsf(x);
  float e = __expf(2.f * a);                 // overflow-safe: e=inf -> r=1
  float r = 1.f - 2.f / (e + 1.f);
  return x < 0.f ? -r : r;
}

// ---------------------------------------------------------------------------
// Kernel 1: x (fp32) -> xb (bf16), flat [B*T][D]
// ---------------------------------------------------------------------------
__global__ __launch_bounds__(256) void k_xconv(const float* __restrict__ x,
                                               unsigned short* __restrict__ xb,
                                               long n4) {
  long i = (long)blockIdx.x * 256 + threadIdx.x;
  long stride = (long)gridDim.x * 256;
  for (; i < n4; i += stride) {
    f32x4 v = *(((const f32x4*)x) + i);
    unsigned long long pk = (unsigned long long)f2bf(v[0])
                          | ((unsigned long long)f2bf(v[1]) << 16)
                          | ((unsigned long long)f2bf(v[2]) << 32)
                          | ((unsigned long long)f2bf(v[3]) << 48);
    *(((unsigned long long*)xb) + i) = pk;
  }
}

// ---------------------------------------------------------------------------
// Kernel 2: build WiT[g][k] = Wi[k][hc(g)] (bf16), WhT[g][k] = Wh[k][hc(g)],
//           bsum[g] = b_i[gate][hc] + b_h[gate][hc]   (g = gate*512 + hc)
// ---------------------------------------------------------------------------
__global__ __launch_bounds__(256) void k_prep(
    const float* wi0, const float* wi1, const float* wi2, const float* wi3,
    const float* wh0, const float* wh1, const float* wh2, const float* wh3,
    const float* bi0, const float* bi1, const float* bi2, const float* bi3,
    const float* bh0, const float* bh1, const float* bh2, const float* bh3,
    unsigned short* __restrict__ WiT, unsigned short* __restrict__ WhT,
    float* __restrict__ bsum) {
  const float* wis[4] = {wi0, wi1, wi2, wi3};
  const float* whs[4] = {wh0, wh1, wh2, wh3};
  const float* bis[4] = {bi0, bi1, bi2, bi3};
  const float* bhs[4] = {bh0, bh1, bh2, bh3};
  int stride = gridDim.x * 256;
  for (int idx = blockIdx.x * 256 + threadIdx.x; idx < 2 * 1048576 + 2048; idx += stride) {
    if (idx < 1048576) {
      int g = idx >> 9, k = idx & 511;
      int gate = g >> 9, hc = g & 511;
      WiT[idx] = f2bf(wis[gate][k * 512 + hc]);
    } else if (idx < 2097152) {
      int j = idx - 1048576;
      int g = j >> 9, k = j & 511;
      int gate = g >> 9, hc = g & 511;
      WhT[j] = f2bf(whs[gate][k * 512 + hc]);
    } else {
      int g = idx - 2097152;
      int gate = g >> 9, hc = g & 511;
      bsum[g] = bis[gate][hc] + bhs[gate][hc];
    }
  }
}

// ---------------------------------------------------------------------------
// Kernel 3: input GEMM  G[t][b][g] = sum_k xb[b*T+t][k] * WiT[g][k]   (bf16 out)
// 128x128 tile, BK=64, 256 thr (4 waves 2x2), 16x16x32 bf16 MFMA,
// XOR-swizzled LDS (row pitch 128B, key (row&7)<<4).
// ---------------------------------------------------------------------------
__global__ __launch_bounds__(256) void k_igemm(const unsigned short* __restrict__ xb,
                                               const unsigned short* __restrict__ WiT,
                                               unsigned short* __restrict__ G) {
  __shared__ char As[16384];
  __shared__ char Bs[16384];
  const int tid  = threadIdx.x;
  const int lane = tid & 63;
  const int wave = tid >> 6;
  const int wm = wave >> 1, wn = wave & 1;
  const int r0 = blockIdx.x * 128;          // rows in [B*T] space (one b per tile)
  const int g0 = blockIdx.y * 128;
  const int bidx = r0 >> 11;
  const int t0   = r0 & 2047;

  f32x4 acc[4][4];
  f32x4 zero = {0.f, 0.f, 0.f, 0.f};
#pragma unroll
  for (int mi = 0; mi < 4; ++mi)
#pragma unroll
    for (int ni = 0; ni < 4; ++ni) acc[mi][ni] = zero;

  for (int kb = 0; kb < 8; ++kb) {
#pragma unroll
    for (int q = 0; q < 4; ++q) {
      int u = tid + q * 256;                // < 1024
      int row = u >> 3, seg = u & 7;        // 8 x 16B per 128B row
      short8 va = *(const short8*)(xb + (size_t)(r0 + row) * 512 + kb * 64 + seg * 8);
      *(short8*)(As + row * 128 + ((seg * 16) ^ ((row & 7) << 4))) = va;
      short8 vb = *(const short8*)(WiT + (size_t)(g0 + row) * 512 + kb * 64 + seg * 8);
      *(short8*)(Bs + row * 128 + ((seg * 16) ^ ((row & 7) << 4))) = vb;
    }
    __syncthreads();
#pragma unroll
    for (int kt = 0; kt < 2; ++kt) {
      int kby = kt * 64 + ((lane >> 4) << 4);
      short8 af[4], bfr[4];
#pragma unroll
      for (int mi = 0; mi < 4; ++mi) {
        int row = wm * 64 + mi * 16 + (lane & 15);
        af[mi] = *(const short8*)(As + row * 128 + (kby ^ ((row & 7) << 4)));
      }
#pragma unroll
      for (int ni = 0; ni < 4; ++ni) {
        int row = wn * 64 + ni * 16 + (lane & 15);
        bfr[ni] = *(const short8*)(Bs + row * 128 + (kby ^ ((row & 7) << 4)));
      }
#pragma unroll
      for (int mi = 0; mi < 4; ++mi)
#pragma unroll
        for (int ni = 0; ni < 4; ++ni)
          acc[mi][ni] = __builtin_amdgcn_mfma_f32_16x16x32_bf16(af[mi], bfr[ni], acc[mi][ni], 0, 0, 0);
    }
    __syncthreads();
  }
  // epilogue: D row = (lane>>4)*4+reg (M), col = lane&15 (N); out layout [t][b][g]
#pragma unroll
  for (int mi = 0; mi < 4; ++mi) {
#pragma unroll
    for (int r = 0; r < 4; ++r) {
      int m = wm * 64 + mi * 16 + ((lane >> 4) << 2) + r;
      size_t orow = ((size_t)(t0 + m) * 64 + bidx) * 2048;
#pragma unroll
      for (int ni = 0; ni < 4; ++ni) {
        int n = wn * 64 + ni * 16 + (lane & 15);
        __builtin_nontemporal_store(f2bf(acc[mi][ni][r]), G + orow + g0 + n);
      }
    }
  }
}

// ---------------------------------------------------------------------------
// Kernel 4: persistent LSTM recurrence.
// 64 WGs x 512 thr. WG w owns h-cols [w*8, w*8+8) => 32 gate cols.
// Sync discipline: ALL cross-WG traffic (h, flags) uses RELAXED agent-scope
// atomics (sc1 -> serviced at the common coherence point, bypassing L1/L2).
// NO acquire loads, NO __threadfence -> zero buffer_inv / wbl2 per step.
// Release ordering: h stores -> __syncthreads (drains vmcnt(0)) -> flag store.
// Acquire ordering: relaxed flag poll; staging loads issued after observation
// are serviced at the same coherence point -> guaranteed to see new h.
// ---------------------------------------------------------------------------
__global__ __launch_bounds__(512) void k_rec(const unsigned short* __restrict__ G,
                                             const unsigned short* __restrict__ WhT,
                                             const float* __restrict__ bsum,
                                             unsigned short* hb0, unsigned short* hb1,
                                             int* flags, float* __restrict__ out) {
  extern __shared__ char smem[];
  char*  Hs   = smem;                        // [64][1024B] swizzled, 64KB
  char*  Bsl  = smem + 65536;                // [32][1024B] swizzled, 32KB
  float* gbuf = (float*)(smem + 98304);      // [64][36] f32 (stride-36 pad), 9216B

  const int tid  = threadIdx.x;
  const int lane = tid & 63;
  const int wave = tid >> 6;
  const int w    = blockIdx.x;               // 0..63
  const int mt   = wave & 3, nt = wave >> 2;
  const int bb   = tid >> 3;                 // batch row (elementwise phase)
  const int jj   = tid & 7;
  const int hc   = w * 8 + jj;

  // Wh slice -> LDS (swizzled), stays resident
#pragma unroll
  for (int q = 0; q < 4; ++q) {
    int u = tid + q * 512;                   // < 2048 (32 rows x 64 segs of 16B)
    int p = u >> 6, seg = u & 63;
    int grow = (p >> 3) * 512 + w * 8 + (p & 7);
    short8 v = *(const short8*)(WhT + (size_t)grow * 512 + seg * 8);
    *(short8*)(Bsl + p * 1024 + ((seg * 16) ^ ((p & 7) << 4))) = v;
  }
  // zero h_0 slice (agent-visible, relaxed sc1 stores)
  if ((jj & 1) == 0)
    __hip_atomic_store((unsigned int*)hb0 + ((bb * 512 + hc) >> 1), 0u,
                       __ATOMIC_RELAXED, __HIP_MEMORY_SCOPE_AGENT);
  float c = 0.f;
  float bias0 = bsum[hc], bias1 = bsum[512 + hc], bias2 = bsum[1024 + hc], bias3 = bsum[1536 + hc];

  asm volatile("s_waitcnt vmcnt(0)" ::: "memory");
  __syncthreads();                           // all zero-stores acked by all threads
  if (tid == 0)
    __hip_atomic_store(flags + w, 1, __ATOMIC_RELAXED, __HIP_MEMORY_SCOPE_AGENT);

  for (int t = 0; t < T_LEN; ++t) {
    // ---- prefetch this step's input-projection gates (h-independent):
    // issue the 4 HBM loads BEFORE the poll so their latency hides under it.
    size_t gbase = ((size_t)t * 64 + bb) * 2048;
    float xi = bf2f(G[gbase + hc]);
    float xf = bf2f(G[gbase + 512 + hc]);
    float xg = bf2f(G[gbase + 1024 + hc]);
    float xo = bf2f(G[gbase + 1536 + hc]);

    // ---- barrier: wait for all WGs to have published h_t (RELAXED poll,
    // no cache invalidates) ----
    if (wave == 0) {
      int target = t + 1;
      while (1) {
        int f = __hip_atomic_load(flags + lane, __ATOMIC_RELAXED, __HIP_MEMORY_SCOPE_AGENT);
        if (__all(f >= target)) break;
        __builtin_amdgcn_s_sleep(1);
      }
    }
    __syncthreads();

    const unsigned long long* hin = (const unsigned long long*)((t & 1) ? hb1 : hb0);
    unsigned short* hout = (t & 1) ? hb0 : hb1;

    // ---- stage h_t [64][512] bf16 -> LDS (swizzled), relaxed sc1 loads ----
#pragma unroll
    for (int q = 0; q < 16; ++q) {
      int u = tid + q * 512;                 // < 8192 (8B granules)
      int row = u >> 7, gr = u & 127;
      unsigned long long v = __hip_atomic_load(hin + u, __ATOMIC_RELAXED, __HIP_MEMORY_SCOPE_AGENT);
      *(unsigned long long*)(Hs + row * 1024 + ((gr * 8) ^ ((row & 7) << 4))) = v;
    }
    __syncthreads();

    // ---- h_t @ Wh_slice : [64x512]x[512x32] ----
    f32x4 acc = {0.f, 0.f, 0.f, 0.f};
#pragma unroll
    for (int kt = 0; kt < 16; ++kt) {
      int kby = kt * 64 + ((lane >> 4) << 4);
      int arow = mt * 16 + (lane & 15);
      short8 a  = *(const short8*)(Hs  + arow * 1024 + (kby ^ ((arow & 7) << 4)));
      int brow = nt * 16 + (lane & 15);
      short8 bv = *(const short8*)(Bsl + brow * 1024 + (kby ^ ((brow & 7) << 4)));
      acc = __builtin_amdgcn_mfma_f32_16x16x32_bf16(a, bv, acc, 0, 0, 0);
    }
    {
      int m  = mt * 16 + ((lane >> 4) << 2);
      int pc = nt * 16 + (lane & 15);
      gbuf[(m + 0) * 36 + pc] = acc[0];
      gbuf[(m + 1) * 36 + pc] = acc[1];
      gbuf[(m + 2) * 36 + pc] = acc[2];
      gbuf[(m + 3) * 36 + pc] = acc[3];
    }
    __syncthreads();

    // ---- gates + state update (thread = (batch bb, h-col jj)) ----
    xi += gbuf[bb * 36 + jj]      + bias0;
    xf += gbuf[bb * 36 + 8 + jj]  + bias1;
    xg += gbuf[bb * 36 + 16 + jj] + bias2;
    xo += gbuf[bb * 36 + 24 + jj] + bias3;
    float iv = sigm(xi), fv = sigm(xf), gv = tanh_f(xg), ov = sigm(xo);
    c = fv * c + iv * gv;
    float h = ov * tanh_f(c);

    // publish h slice (pack bf16 pairs -> u32 relaxed agent stores)
    unsigned short hu = f2bf(h);
    unsigned int other = __shfl_xor((unsigned int)hu, 1);
    if ((jj & 1) == 0) {
      unsigned int val = (unsigned int)hu | (other << 16);
      __hip_atomic_store((unsigned int*)hout + ((bb * 512 + hc) >> 1), val,
                         __ATOMIC_RELAXED, __HIP_MEMORY_SCOPE_AGENT);
    }
    // release: drain all h stores (vmcnt ack at coherence point) across the
    // whole WG, then publish the flag. No wbl2/inv needed (stores are sc1).
    asm volatile("s_waitcnt vmcnt(0)" ::: "memory");
    __syncthreads();
    if (tid == 0)
      __hip_atomic_store(flags + w, t + 2, __ATOMIC_RELAXED, __HIP_MEMORY_SCOPE_AGENT);

    if (t == T_LEN - 1) {
      out[bb * 512 + hc] = h;                // h_T
      out[32768 + bb * 512 + hc] = c;        // c_T
    }
  }
}

// ---------------------------------------------------------------------------
extern "C" void kernel_launch(void* const* d_in, const int* in_sizes, int n_in,
                              void* d_out, int out_size, void* d_ws, size_t ws_size,
                              hipStream_t stream) {
  const float* x   = (const float*)d_in[0];
  const float* wi0 = (const float*)d_in[1];
  const float* wi1 = (const float*)d_in[2];
  const float* wi2 = (const float*)d_in[3];
  const float* wi3 = (const float*)d_in[4];
  const float* wh0 = (const float*)d_in[5];
  const float* wh1 = (const float*)d_in[6];
  const float* wh2 = (const float*)d_in[7];
  const float* wh3 = (const float*)d_in[8];
  const float* bi0 = (const float*)d_in[9];
  const float* bi1 = (const float*)d_in[10];
  const float* bi2 = (const float*)d_in[11];
  const float* bi3 = (const float*)d_in[12];
  const float* bh0 = (const float*)d_in[13];
  const float* bh1 = (const float*)d_in[14];
  const float* bh2 = (const float*)d_in[15];
  const float* bh3 = (const float*)d_in[16];

  char* ws = (char*)d_ws;
  unsigned short* xb   = (unsigned short*)(ws);                               // 134217728 B
  unsigned short* G    = (unsigned short*)(ws + 134217728);                   // 536870912 B
  unsigned short* WiT  = (unsigned short*)(ws + 671088640);                   // 2097152 B
  unsigned short* WhT  = (unsigned short*)(ws + 673185792);                   // 2097152 B
  float*          bsum = (float*)         (ws + 675282944);                   // 8192 B
  unsigned short* hb0  = (unsigned short*)(ws + 675291136);                   // 65536 B
  unsigned short* hb1  = (unsigned short*)(ws + 675356672);                   // 65536 B
  int*            flags= (int*)           (ws + 675422208);                   // 256 B
  float* out = (float*)d_out;

  (void)hipFuncSetAttribute(reinterpret_cast<const void*>(k_rec),
                            hipFuncAttributeMaxDynamicSharedMemorySize, 107520);

  k_xconv<<<8192, 256, 0, stream>>>(x, xb, 16777216L);
  k_prep<<<2048, 256, 0, stream>>>(wi0, wi1, wi2, wi3, wh0, wh1, wh2, wh3,
                                   bi0, bi1, bi2, bi3, bh0, bh1, bh2, bh3,
                                   WiT, WhT, bsum);
  k_igemm<<<dim3(1024, 16), 256, 0, stream>>>(xb, WiT, G);
  k_rec<<<64, 512, 107520, stream>>>(G, WhT, bsum, hb0, hb1, flags, out);
}

// Round 6
// 9629.713 us; speedup vs baseline: 2.5253x; 1.5351x over previous
//
#include <hip/hip_runtime.h>
#include <stdint.h>
#include <stddef.h>

// Problem dims
#define T_LEN 2048
#define BATCH 64
#define DDIM  512
#define HDIM  512

typedef short  short8  __attribute__((ext_vector_type(8)));
typedef float  f32x4   __attribute__((ext_vector_type(4)));

static __device__ __forceinline__ unsigned short f2bf(float f) {
  unsigned int u = __builtin_bit_cast(unsigned int, f);
  u += 0x7FFFu + ((u >> 16) & 1u);          // round-to-nearest-even
  return (unsigned short)(u >> 16);
}
static __device__ __forceinline__ float bf2f(unsigned short s) {
  unsigned int u = ((unsigned int)s) << 16;
  return __builtin_bit_cast(float, u);
}
static __device__ __forceinline__ float sigm(float x) {
  return 1.f / (1.f + __expf(-x));
}
static __device__ __forceinline__ float tanh_f(float x) {
  float a = fabsf(x);
  float e = __expf(2.f * a);                 // overflow-safe: e=inf -> r=1
  float r = 1.f - 2.f / (e + 1.f);
  return x < 0.f ? -r : r;
}

// ---------------------------------------------------------------------------
// Kernel 1: x (fp32) -> xb (bf16), flat [B*T][D]
// ---------------------------------------------------------------------------
__global__ __launch_bounds__(256) void k_xconv(const float* __restrict__ x,
                                               unsigned short* __restrict__ xb,
                                               long n4) {
  long i = (long)blockIdx.x * 256 + threadIdx.x;
  long stride = (long)gridDim.x * 256;
  for (; i < n4; i += stride) {
    f32x4 v = *(((const f32x4*)x) + i);
    unsigned long long pk = (unsigned long long)f2bf(v[0])
                          | ((unsigned long long)f2bf(v[1]) << 16)
                          | ((unsigned long long)f2bf(v[2]) << 32)
                          | ((unsigned long long)f2bf(v[3]) << 48);
    *(((unsigned long long*)xb) + i) = pk;
  }
}

// ---------------------------------------------------------------------------
// Kernel 2: build WiT[g][k] = Wi[k][hc(g)] (bf16), WhT[g][k] = Wh[k][hc(g)],
//           bsum[g] = b_i[gate][hc] + b_h[gate][hc]   (g = gate*512 + hc)
// ---------------------------------------------------------------------------
__global__ __launch_bounds__(256) void k_prep(
    const float* wi0, const float* wi1, const float* wi2, const float* wi3,
    const float* wh0, const float* wh1, const float* wh2, const float* wh3,
    const float* bi0, const float* bi1, const float* bi2, const float* bi3,
    const float* bh0, const float* bh1, const float* bh2, const float* bh3,
    unsigned short* __restrict__ WiT, unsigned short* __restrict__ WhT,
    float* __restrict__ bsum) {
  const float* wis[4] = {wi0, wi1, wi2, wi3};
  const float* whs[4] = {wh0, wh1, wh2, wh3};
  const float* bis[4] = {bi0, bi1, bi2, bi3};
  const float* bhs[4] = {bh0, bh1, bh2, bh3};
  int stride = gridDim.x * 256;
  for (int idx = blockIdx.x * 256 + threadIdx.x; idx < 2 * 1048576 + 2048; idx += stride) {
    if (idx < 1048576) {
      int g = idx >> 9, k = idx & 511;
      int gate = g >> 9, hc = g & 511;
      WiT[idx] = f2bf(wis[gate][k * 512 + hc]);
    } else if (idx < 2097152) {
      int j = idx - 1048576;
      int g = j >> 9, k = j & 511;
      int gate = g >> 9, hc = g & 511;
      WhT[j] = f2bf(whs[gate][k * 512 + hc]);
    } else {
      int g = idx - 2097152;
      int gate = g >> 9, hc = g & 511;
      bsum[g] = bis[gate][hc] + bhs[gate][hc];
    }
  }
}

// ---------------------------------------------------------------------------
// Kernel 3: input GEMM  G[t][b][g] = sum_k xb[b*T+t][k] * WiT[g][k]   (bf16 out)
// 128x128 tile, BK=64, 256 thr (4 waves 2x2), 16x16x32 bf16 MFMA,
// XOR-swizzled LDS (row pitch 128B, key (row&7)<<4).
// ---------------------------------------------------------------------------
__global__ __launch_bounds__(256) void k_igemm(const unsigned short* __restrict__ xb,
                                               const unsigned short* __restrict__ WiT,
                                               unsigned short* __restrict__ G) {
  __shared__ char As[16384];
  __shared__ char Bs[16384];
  const int tid  = threadIdx.x;
  const int lane = tid & 63;
  const int wave = tid >> 6;
  const int wm = wave >> 1, wn = wave & 1;
  const int r0 = blockIdx.x * 128;          // rows in [B*T] space (one b per tile)
  const int g0 = blockIdx.y * 128;
  const int bidx = r0 >> 11;
  const int t0   = r0 & 2047;

  f32x4 acc[4][4];
  f32x4 zero = {0.f, 0.f, 0.f, 0.f};
#pragma unroll
  for (int mi = 0; mi < 4; ++mi)
#pragma unroll
    for (int ni = 0; ni < 4; ++ni) acc[mi][ni] = zero;

  for (int kb = 0; kb < 8; ++kb) {
#pragma unroll
    for (int q = 0; q < 4; ++q) {
      int u = tid + q * 256;                // < 1024
      int row = u >> 3, seg = u & 7;        // 8 x 16B per 128B row
      short8 va = *(const short8*)(xb + (size_t)(r0 + row) * 512 + kb * 64 + seg * 8);
      *(short8*)(As + row * 128 + ((seg * 16) ^ ((row & 7) << 4))) = va;
      short8 vb = *(const short8*)(WiT + (size_t)(g0 + row) * 512 + kb * 64 + seg * 8);
      *(short8*)(Bs + row * 128 + ((seg * 16) ^ ((row & 7) << 4))) = vb;
    }
    __syncthreads();
#pragma unroll
    for (int kt = 0; kt < 2; ++kt) {
      int kby = kt * 64 + ((lane >> 4) << 4);
      short8 af[4], bfr[4];
#pragma unroll
      for (int mi = 0; mi < 4; ++mi) {
        int row = wm * 64 + mi * 16 + (lane & 15);
        af[mi] = *(const short8*)(As + row * 128 + (kby ^ ((row & 7) << 4)));
      }
#pragma unroll
      for (int ni = 0; ni < 4; ++ni) {
        int row = wn * 64 + ni * 16 + (lane & 15);
        bfr[ni] = *(const short8*)(Bs + row * 128 + (kby ^ ((row & 7) << 4)));
      }
#pragma unroll
      for (int mi = 0; mi < 4; ++mi)
#pragma unroll
        for (int ni = 0; ni < 4; ++ni)
          acc[mi][ni] = __builtin_amdgcn_mfma_f32_16x16x32_bf16(af[mi], bfr[ni], acc[mi][ni], 0, 0, 0);
    }
    __syncthreads();
  }
  // epilogue: D row = (lane>>4)*4+reg (M), col = lane&15 (N); out layout [t][b][g]
#pragma unroll
  for (int mi = 0; mi < 4; ++mi) {
#pragma unroll
    for (int r = 0; r < 4; ++r) {
      int m = wm * 64 + mi * 16 + ((lane >> 4) << 2) + r;
      size_t orow = ((size_t)(t0 + m) * 64 + bidx) * 2048;
#pragma unroll
      for (int ni = 0; ni < 4; ++ni) {
        int n = wn * 64 + ni * 16 + (lane & 15);
        __builtin_nontemporal_store(f2bf(acc[mi][ni][r]), G + orow + g0 + n);
      }
    }
  }
}

// ---------------------------------------------------------------------------
// Kernel 4: persistent LSTM recurrence — frag-layout h exchange, no staging.
// 64 WGs x 512 thr (8 waves = 4 mt x 2 nt). WG w owns h-cols [w*8,w*8+8).
// h buffers are stored in MFMA A-FRAGMENT layout:
//   16B chunk index = (kt*4 + mt)*64 + lane, holding rows (bb&15)=lane&15 of
//   k-cols kt*32 + (lane>>4)*8 .. +8. Producers store h directly into this
//   layout (2x 8B agent stores per bb, packed via 2 shfl_xor); consumers load
//   A-frags straight to registers (16x 8B agent loads/lane) — no LDS staging.
// Wh B-frags live in REGISTERS for all 2048 steps (64 VGPR/lane).
// Waves split the k-range (nt = k-half); partial sums meet in gbuf[2][][].
// Sync protocol (unchanged, verified round-5): relaxed sc1 atomics only,
// release = vmcnt(0) drain + __syncthreads before flag store.
// ---------------------------------------------------------------------------
__global__ __launch_bounds__(512) void k_rec(const unsigned short* __restrict__ G,
                                             const unsigned short* __restrict__ WhT,
                                             const float* __restrict__ bsum,
                                             unsigned long long* hb0, unsigned long long* hb1,
                                             int* flags, float* __restrict__ out) {
  __shared__ float gbuf[2][64][36];          // [k-half][batch][gate-col], pad 36

  const int tid  = threadIdx.x;
  const int lane = tid & 63;
  const int wave = tid >> 6;                 // 0..7
  const int w    = blockIdx.x;               // 0..63
  const int mt   = wave & 3;                 // batch 16-row group
  const int nt   = wave >> 2;                // k-half (0/1)
  const int bb   = tid >> 3;                 // batch row (elementwise phase)
  const int jj   = tid & 7;                  // local h-col
  const int hc   = w * 8 + jj;

  // ---- preload Wh B-frags into registers (resident for all steps) ----
  short8 bfrag[8][2];
#pragma unroll
  for (int kt = 0; kt < 8; ++kt) {
#pragma unroll
    for (int ni = 0; ni < 2; ++ni) {
      int cc   = ni * 16 + (lane & 15);                  // local gate-col 0..31
      int grow = (cc >> 3) * 512 + w * 8 + (cc & 7);     // global gate row in WhT
      int kk   = (nt * 8 + kt) * 32 + ((lane >> 4) << 3);
      bfrag[kt][ni] = *(const short8*)(WhT + (size_t)grow * 512 + kk);
    }
  }

  // producer slot: 16B chunk for (bb, this WG's 8 cols); 8B slot adds jj>>2
  const int pchunk = (((w >> 2) * 4 + (bb >> 4)) * 64) + ((w & 3) * 16) + (bb & 15);
  const int pslot  = pchunk * 2 + (jj >> 2);
  const bool leader = ((jj & 3) == 0);

  // zero h_0 slice (frag layout, agent-visible)
  if (leader)
    __hip_atomic_store(hb0 + pslot, 0ULL, __ATOMIC_RELAXED, __HIP_MEMORY_SCOPE_AGENT);

  float c = 0.f;
  float bias0 = bsum[hc], bias1 = bsum[512 + hc], bias2 = bsum[1024 + hc], bias3 = bsum[1536 + hc];

  asm volatile("s_waitcnt vmcnt(0)" ::: "memory");
  __syncthreads();
  if (tid == 0)
    __hip_atomic_store(flags + w, 1, __ATOMIC_RELAXED, __HIP_MEMORY_SCOPE_AGENT);

  for (int t = 0; t < T_LEN; ++t) {
    // ---- prefetch this step's input-projection gates before the poll ----
    size_t gbase = ((size_t)t * 64 + bb) * 2048;
    float xi = bf2f(G[gbase + hc]);
    float xf = bf2f(G[gbase + 512 + hc]);
    float xg = bf2f(G[gbase + 1024 + hc]);
    float xo = bf2f(G[gbase + 1536 + hc]);

    // ---- barrier: wait for all WGs to have published h_t ----
    if (wave == 0) {
      int target = t + 1;
      while (1) {
        int f = __hip_atomic_load(flags + lane, __ATOMIC_RELAXED, __HIP_MEMORY_SCOPE_AGENT);
        if (__all(f >= target)) break;
        __builtin_amdgcn_s_sleep(2);
      }
    }
    __syncthreads();

    const unsigned long long* hin = (t & 1) ? hb1 : hb0;
    unsigned long long*       hout = (t & 1) ? hb0 : hb1;

    // ---- load A-frags for this wave's k-half directly to registers ----
    unsigned long long alo[8], ahi[8];
#pragma unroll
    for (int kt = 0; kt < 8; ++kt) {
      int chunk = ((nt * 8 + kt) * 4 + mt) * 64 + lane;
      alo[kt] = __hip_atomic_load(hin + chunk * 2 + 0, __ATOMIC_RELAXED, __HIP_MEMORY_SCOPE_AGENT);
      ahi[kt] = __hip_atomic_load(hin + chunk * 2 + 1, __ATOMIC_RELAXED, __HIP_MEMORY_SCOPE_AGENT);
    }

    // ---- MFMA over this k-half: [16 batch x 512/2 k] x [k x 32 gate-cols] ----
    f32x4 acc0 = {0.f, 0.f, 0.f, 0.f};
    f32x4 acc1 = {0.f, 0.f, 0.f, 0.f};
#pragma unroll
    for (int kt = 0; kt < 8; ++kt) {
      union { unsigned long long q[2]; short8 s; } u;
      u.q[0] = alo[kt]; u.q[1] = ahi[kt];
      acc0 = __builtin_amdgcn_mfma_f32_16x16x32_bf16(u.s, bfrag[kt][0], acc0, 0, 0, 0);
      acc1 = __builtin_amdgcn_mfma_f32_16x16x32_bf16(u.s, bfrag[kt][1], acc1, 0, 0, 0);
    }

    // ---- write k-half partial sums to gbuf (2 lanes/bank — conflict-free) ----
    {
      int m  = mt * 16 + ((lane >> 4) << 2);
      int pc = lane & 15;
#pragma unroll
      for (int r = 0; r < 4; ++r) {
        gbuf[nt][m + r][pc]      = acc0[r];
        gbuf[nt][m + r][16 + pc] = acc1[r];
      }
    }
    __syncthreads();

    // ---- gates + state update (thread = (batch bb, h-col jj)) ----
    xi += gbuf[0][bb][jj]      + gbuf[1][bb][jj]      + bias0;
    xf += gbuf[0][bb][8 + jj]  + gbuf[1][bb][8 + jj]  + bias1;
    xg += gbuf[0][bb][16 + jj] + gbuf[1][bb][16 + jj] + bias2;
    xo += gbuf[0][bb][24 + jj] + gbuf[1][bb][24 + jj] + bias3;
    float iv = sigm(xi), fv = sigm(xf), gv = tanh_f(xg), ov = sigm(xo);
    c = fv * c + iv * gv;
    float h = ov * tanh_f(c);

    // ---- publish h_{t+1} in frag layout: pack 4 cols -> u64, leaders store ----
    unsigned int hu = (unsigned int)f2bf(h);
    unsigned int s1 = (unsigned int)__shfl_xor((int)hu, 1);
    unsigned int pr = (jj & 1) ? (s1 | (hu << 16)) : (hu | (s1 << 16));
    unsigned int s2 = (unsigned int)__shfl_xor((int)pr, 2);
    unsigned long long v64 = (jj & 2)
        ? ((unsigned long long)s2 | ((unsigned long long)pr << 32))
        : ((unsigned long long)pr | ((unsigned long long)s2 << 32));
    if (leader)
      __hip_atomic_store(hout + pslot, v64, __ATOMIC_RELAXED, __HIP_MEMORY_SCOPE_AGENT);

    // release: drain own stores, then WG-wide barrier, then flag publish
    asm volatile("s_waitcnt vmcnt(0)" ::: "memory");
    __syncthreads();
    if (tid == 0)
      __hip_atomic_store(flags + w, t + 2, __ATOMIC_RELAXED, __HIP_MEMORY_SCOPE_AGENT);

    if (t == T_LEN - 1) {
      out[bb * 512 + hc] = h;                // h_T
      out[32768 + bb * 512 + hc] = c;        // c_T
    }
  }
}

// ---------------------------------------------------------------------------
extern "C" void kernel_launch(void* const* d_in, const int* in_sizes, int n_in,
                              void* d_out, int out_size, void* d_ws, size_t ws_size,
                              hipStream_t stream) {
  const float* x   = (const float*)d_in[0];
  const float* wi0 = (const float*)d_in[1];
  const float* wi1 = (const float*)d_in[2];
  const float* wi2 = (const float*)d_in[3];
  const float* wi3 = (const float*)d_in[4];
  const float* wh0 = (const float*)d_in[5];
  const float* wh1 = (const float*)d_in[6];
  const float* wh2 = (const float*)d_in[7];
  const float* wh3 = (const float*)d_in[8];
  const float* bi0 = (const float*)d_in[9];
  const float* bi1 = (const float*)d_in[10];
  const float* bi2 = (const float*)d_in[11];
  const float* bi3 = (const float*)d_in[12];
  const float* bh0 = (const float*)d_in[13];
  const float* bh1 = (const float*)d_in[14];
  const float* bh2 = (const float*)d_in[15];
  const float* bh3 = (const float*)d_in[16];

  char* ws = (char*)d_ws;
  unsigned short* xb   = (unsigned short*)(ws);                               // 134217728 B
  unsigned short* G    = (unsigned short*)(ws + 134217728);                   // 536870912 B
  unsigned short* WiT  = (unsigned short*)(ws + 671088640);                   // 2097152 B
  unsigned short* WhT  = (unsigned short*)(ws + 673185792);                   // 2097152 B
  float*          bsum = (float*)         (ws + 675282944);                   // 8192 B
  unsigned long long* hb0 = (unsigned long long*)(ws + 675291136);            // 65536 B (frag layout)
  unsigned long long* hb1 = (unsigned long long*)(ws + 675356672);            // 65536 B (frag layout)
  int*            flags= (int*)           (ws + 675422208);                   // 256 B
  float* out = (float*)d_out;

  k_xconv<<<8192, 256, 0, stream>>>(x, xb, 16777216L);
  k_prep<<<2048, 256, 0, stream>>>(wi0, wi1, wi2, wi3, wh0, wh1, wh2, wh3,
                                   bi0, bi1, bi2, bi3, bh0, bh1, bh2, bh3,
                                   WiT, WhT, bsum);
  k_igemm<<<dim3(1024, 16), 256, 0, stream>>>(xb, WiT, G);
  k_rec<<<64, 512, 0, stream>>>(G, WhT, bsum, hb0, hb1, flags, out);
}